// Round 1
// baseline (836.520 us; speedup 1.0000x reference)
//
#include <hip/hip_runtime.h>

typedef unsigned short u16;
typedef __attribute__((ext_vector_type(8))) short bf16x8;   // 8 bf16 in 4 VGPRs
typedef __attribute__((ext_vector_type(4))) float f32x4;

__device__ __forceinline__ u16 f2bf(float f) {
    union { float f; unsigned u; } v; v.f = f;
    unsigned r = v.u + 0x7fffu + ((v.u >> 16) & 1u);   // RNE
    return (u16)(r >> 16);
}

// ---------------- Kernel 1: GroupNorm stats ----------------
// 128 blocks = (b,g); each group is 4 channels * 4096 spatial = 16384 contiguous floats.
__global__ __launch_bounds__(256)
void k_stats(const float* __restrict__ x, float* __restrict__ mean, float* __restrict__ rstd)
{
    int bg = blockIdx.x, t = threadIdx.x;
    const float4* xp = (const float4*)(x + (size_t)bg * 16384);
    float s1 = 0.f, s2 = 0.f;
#pragma unroll
    for (int i = 0; i < 16; ++i) {
        float4 v = xp[i * 256 + t];
        s1 += v.x + v.y + v.z + v.w;
        s2 += v.x * v.x + v.y * v.y + v.z * v.z + v.w * v.w;
    }
#pragma unroll
    for (int off = 32; off >= 1; off >>= 1) {
        s1 += __shfl_xor(s1, off);
        s2 += __shfl_xor(s2, off);
    }
    __shared__ float a1[4], a2[4];
    if ((t & 63) == 0) { a1[t >> 6] = s1; a2[t >> 6] = s2; }
    __syncthreads();
    if (t == 0) {
        float t1 = a1[0] + a1[1] + a1[2] + a1[3];
        float t2 = a2[0] + a2[1] + a2[2] + a2[3];
        float mu = t1 * (1.f / 16384.f);
        float var = t2 * (1.f / 16384.f) - mu * mu;
        mean[bg] = mu;
        rstd[bg] = rsqrtf(var + 1e-5f);
    }
}

// ---------------- Kernel 2: normalize + QKV pointwise GEMM ----------------
// grid 256 = (b, ntile of 64); 384 threads, thread t owns output channel o=t.
// Writes: Q,K as (b,n,c) bf16 (rows contiguous in c), V as (b,c,n) bf16 (transposed).
__global__ __launch_bounds__(384)
void k_qkv(const float* __restrict__ x, const float* __restrict__ gn_w, const float* __restrict__ gn_b,
           const float* __restrict__ qkv_w, const float* __restrict__ qkv_b,
           const float* __restrict__ mean, const float* __restrict__ rstd,
           u16* __restrict__ Qo, u16* __restrict__ Ko, u16* __restrict__ Vo)
{
    __shared__ float xn[128][64];   // 32 KB, [channel][n-local]
    int t = threadIdx.x;
    int b = blockIdx.x >> 6;
    int n0 = (blockIdx.x & 63) << 6;

    for (int e = t; e < 8192; e += 384) {
        int c = e >> 6, nn = e & 63;
        int bg = (b << 5) + (c >> 2);
        float sc = rstd[bg] * gn_w[c];
        float sh = gn_b[c] - mean[bg] * sc;
        xn[c][nn] = x[(size_t)(b * 128 + c) * 4096 + n0 + nn] * sc + sh;
    }
    __syncthreads();

    int o = t;                       // 0..383 output channel
    float acc[64];
    float bias = qkv_b[o];
#pragma unroll
    for (int j = 0; j < 64; ++j) acc[j] = bias;

    const float4* wrow = (const float4*)(qkv_w + (size_t)o * 128);
    for (int c4 = 0; c4 < 32; ++c4) {
        float4 w4 = wrow[c4];
#pragma unroll
        for (int i = 0; i < 4; ++i) {
            int c = c4 * 4 + i;
            float wv = (i == 0) ? w4.x : (i == 1) ? w4.y : (i == 2) ? w4.z : w4.w;
#pragma unroll
            for (int j4 = 0; j4 < 16; ++j4) {
                float4 xv = *(const float4*)&xn[c][j4 * 4];
                acc[j4 * 4 + 0] = fmaf(xv.x, wv, acc[j4 * 4 + 0]);
                acc[j4 * 4 + 1] = fmaf(xv.y, wv, acc[j4 * 4 + 1]);
                acc[j4 * 4 + 2] = fmaf(xv.z, wv, acc[j4 * 4 + 2]);
                acc[j4 * 4 + 3] = fmaf(xv.w, wv, acc[j4 * 4 + 3]);
            }
        }
    }

    if (o < 128) {                                   // Q -> (b,n,c)
        size_t base = (size_t)(b * 4096 + n0) * 128 + o;
#pragma unroll 8
        for (int nn = 0; nn < 64; ++nn) Qo[base + (size_t)nn * 128] = f2bf(acc[nn]);
    } else if (o < 256) {                            // K -> (b,n,c)
        size_t base = (size_t)(b * 4096 + n0) * 128 + (o - 128);
#pragma unroll 8
        for (int nn = 0; nn < 64; ++nn) Ko[base + (size_t)nn * 128] = f2bf(acc[nn]);
    } else {                                         // V -> (b,c,n), vectorized 8x bf16
        size_t base = (size_t)(b * 128 + (o - 256)) * 4096 + n0;
#pragma unroll
        for (int g = 0; g < 8; ++g) {
            uint4 pk;
            pk.x = ((unsigned)f2bf(acc[g * 8 + 1]) << 16) | f2bf(acc[g * 8 + 0]);
            pk.y = ((unsigned)f2bf(acc[g * 8 + 3]) << 16) | f2bf(acc[g * 8 + 2]);
            pk.z = ((unsigned)f2bf(acc[g * 8 + 5]) << 16) | f2bf(acc[g * 8 + 4]);
            pk.w = ((unsigned)f2bf(acc[g * 8 + 7]) << 16) | f2bf(acc[g * 8 + 6]);
            *(uint4*)&Vo[base + g * 8] = pk;
        }
    }
}

// ---------------- Kernel 3: flash attention (KV-split = 2) ----------------
// grid 512: blk = b*128 + qt*2 + half. 4 waves; wave w owns q rows q0+w*16..+15.
// mfma_f32_16x16x32_bf16: A lane: row=l&15, k=(l>>4)*8+j ; D lane: col=l&15, row=(l>>4)*4+r.
__global__ __launch_bounds__(256)
void k_attn(const u16* __restrict__ Qg, const u16* __restrict__ Kg, const u16* __restrict__ Vg,
            float* __restrict__ Opart, float* __restrict__ ml)
{
    __shared__ __align__(16) u16 Kl[64][136];    // padded: row stride 272B
    __shared__ __align__(16) u16 Vl[128][72];    // [c][kv-local], stride 144B
    __shared__ __align__(16) u16 Pl[4][16][72];  // per-wave P tile

    const int t = threadIdx.x;
    const int blk = blockIdx.x;
    const int half = blk & 1;
    const int qt = (blk >> 1) & 63;
    const int b = blk >> 7;
    const int w = t >> 6;
    const int lane = t & 63;
    const int l15 = lane & 15;
    const int l4 = lane >> 4;
    const int q0 = qt << 6;

    bf16x8 qf[4];
    {
        const u16* qb = Qg + (size_t)(b * 4096 + q0 + w * 16 + l15) * 128 + l4 * 8;
#pragma unroll
        for (int kc = 0; kc < 4; ++kc) qf[kc] = *(const bf16x8*)(qb + kc * 32);
    }
    f32x4 oac[8];
#pragma unroll
    for (int cf = 0; cf < 8; ++cf) oac[cf] = (f32x4){0.f, 0.f, 0.f, 0.f};
    float m[4], ls[4];
#pragma unroll
    for (int r = 0; r < 4; ++r) { m[r] = -__builtin_inff(); ls[r] = 0.f; }

    const int kvbeg = half << 11;
    const float scale = 0.08838834764831845f;   // 128^-0.5

    for (int kv0 = kvbeg; kv0 < kvbeg + 2048; kv0 += 64) {
        // stage K (64x128) and V^T (128x64) into LDS
#pragma unroll
        for (int i = 0; i < 4; ++i) {
            int e = i * 256 + t;
            int kr = e >> 4, kch = e & 15;
            *(uint4*)&Kl[kr][kch * 8] =
                *(const uint4*)(Kg + (size_t)(b * 4096 + kv0 + kr) * 128 + kch * 8);
            int vr = e >> 3, vch = e & 7;
            *(uint4*)&Vl[vr][vch * 8] =
                *(const uint4*)(Vg + (size_t)(b * 128 + vr) * 4096 + kv0 + vch * 8);
        }
        __syncthreads();

        // S = Q K^T * scale   (4 m-subtiles of 16)
        f32x4 st[4];
#pragma unroll
        for (int mt = 0; mt < 4; ++mt) {
            f32x4 s = (f32x4){0.f, 0.f, 0.f, 0.f};
#pragma unroll
            for (int kc = 0; kc < 4; ++kc) {
                bf16x8 kf = *(const bf16x8*)&Kl[mt * 16 + l15][kc * 32 + l4 * 8];
                s = __builtin_amdgcn_mfma_f32_16x16x32_bf16(qf[kc], kf, s, 0, 0, 0);
            }
#pragma unroll
            for (int r = 0; r < 4; ++r) st[mt][r] = s[r] * scale;
        }

        // online softmax: row groups are the 16 lanes sharing l>>4
        float rmax[4], rsum[4], fr[4];
#pragma unroll
        for (int r = 0; r < 4; ++r) {
            float v = fmaxf(fmaxf(st[0][r], st[1][r]), fmaxf(st[2][r], st[3][r]));
            v = fmaxf(v, __shfl_xor(v, 1));
            v = fmaxf(v, __shfl_xor(v, 2));
            v = fmaxf(v, __shfl_xor(v, 4));
            v = fmaxf(v, __shfl_xor(v, 8));
            rmax[r] = v;
        }
#pragma unroll
        for (int r = 0; r < 4; ++r) {
            float nm = fmaxf(m[r], rmax[r]);
            fr[r] = __expf(m[r] - nm);
            m[r] = nm;
            rsum[r] = 0.f;
        }
#pragma unroll
        for (int mt = 0; mt < 4; ++mt)
#pragma unroll
            for (int r = 0; r < 4; ++r) {
                float p = __expf(st[mt][r] - m[r]);
                st[mt][r] = p;
                rsum[r] += p;
            }
#pragma unroll
        for (int r = 0; r < 4; ++r) {
            float v = rsum[r];
            v += __shfl_xor(v, 1);
            v += __shfl_xor(v, 2);
            v += __shfl_xor(v, 4);
            v += __shfl_xor(v, 8);
            ls[r] = ls[r] * fr[r] + v;
        }
#pragma unroll
        for (int cf = 0; cf < 8; ++cf)
#pragma unroll
            for (int r = 0; r < 4; ++r) oac[cf][r] *= fr[r];

        // P (D-layout) -> LDS -> A-layout for PV
#pragma unroll
        for (int mt = 0; mt < 4; ++mt)
#pragma unroll
            for (int r = 0; r < 4; ++r)
                Pl[w][l4 * 4 + r][mt * 16 + l15] = f2bf(st[mt][r]);
        asm volatile("s_waitcnt lgkmcnt(0)" ::: "memory");
        __builtin_amdgcn_sched_barrier(0);

#pragma unroll
        for (int kc2 = 0; kc2 < 2; ++kc2) {
            bf16x8 pf = *(const bf16x8*)&Pl[w][l15][kc2 * 32 + l4 * 8];
#pragma unroll
            for (int cf = 0; cf < 8; ++cf) {
                bf16x8 vf = *(const bf16x8*)&Vl[cf * 16 + l15][kc2 * 32 + l4 * 8];
                oac[cf] = __builtin_amdgcn_mfma_f32_16x16x32_bf16(pf, vf, oac[cf], 0, 0, 0);
            }
        }
        __syncthreads();
    }

    // write unnormalized partials + (m, l)
    {
        size_t rb = ((size_t)half * 4 + b) * 4096 + q0 + w * 16 + l4 * 4;
#pragma unroll
        for (int cf = 0; cf < 8; ++cf)
#pragma unroll
            for (int r = 0; r < 4; ++r)
                Opart[(rb + r) * 128 + cf * 16 + l15] = oac[cf][r];
        if (l15 == 0) {
            size_t mb = (size_t)half * 16384 + b * 4096 + q0 + w * 16 + l4 * 4;
#pragma unroll
            for (int r = 0; r < 4; ++r) {
                ml[(mb + r) * 2 + 0] = m[r];
                ml[(mb + r) * 2 + 1] = ls[r];
            }
        }
    }
}

// ---------------- Kernel 4: merge halves + out-proj + bias + residual ----------------
// grid 256 = (b, ntile 64); 256 threads; thread owns oc=t&127, n-half nh=t>>7.
__global__ __launch_bounds__(256)
void k_proj(const float* __restrict__ Opart, const float* __restrict__ ml,
            const float* __restrict__ x, const float* __restrict__ out_w,
            const float* __restrict__ out_b, float* __restrict__ out)
{
    __shared__ float Ol[128][64];   // [c][n-local] merged attention output
    int t = threadIdx.x;
    int b = blockIdx.x >> 6;
    int n0 = (blockIdx.x & 63) << 6;

    for (int e = t; e < 2048; e += 256) {
        int nn = e >> 5, c4 = e & 31;
        size_t rg = (size_t)b * 4096 + n0 + nn;
        float m1 = ml[rg * 2], l1 = ml[rg * 2 + 1];
        float m2 = ml[(rg + 16384) * 2], l2 = ml[(rg + 16384) * 2 + 1];
        float mm = fmaxf(m1, m2);
        float e1 = __expf(m1 - mm), e2 = __expf(m2 - mm);
        float inv = 1.f / (l1 * e1 + l2 * e2);
        float4 o1 = *(const float4*)&Opart[rg * 128 + c4 * 4];
        float4 o2 = *(const float4*)&Opart[(rg + 16384) * 128 + c4 * 4];
        Ol[c4 * 4 + 0][nn] = (o1.x * e1 + o2.x * e2) * inv;
        Ol[c4 * 4 + 1][nn] = (o1.y * e1 + o2.y * e2) * inv;
        Ol[c4 * 4 + 2][nn] = (o1.z * e1 + o2.z * e2) * inv;
        Ol[c4 * 4 + 3][nn] = (o1.w * e1 + o2.w * e2) * inv;
    }
    __syncthreads();

    int oc = t & 127, nh = t >> 7;
    float acc[32];
    float bias = out_b[oc];
#pragma unroll
    for (int j = 0; j < 32; ++j) acc[j] = bias;

    const float4* wrow = (const float4*)(out_w + (size_t)oc * 128);
    for (int c4 = 0; c4 < 32; ++c4) {
        float4 w4 = wrow[c4];
#pragma unroll
        for (int i = 0; i < 4; ++i) {
            int c = c4 * 4 + i;
            float wv = (i == 0) ? w4.x : (i == 1) ? w4.y : (i == 2) ? w4.z : w4.w;
#pragma unroll
            for (int j4 = 0; j4 < 8; ++j4) {
                float4 xv = *(const float4*)&Ol[c][nh * 32 + j4 * 4];
                acc[j4 * 4 + 0] = fmaf(xv.x, wv, acc[j4 * 4 + 0]);
                acc[j4 * 4 + 1] = fmaf(xv.y, wv, acc[j4 * 4 + 1]);
                acc[j4 * 4 + 2] = fmaf(xv.z, wv, acc[j4 * 4 + 2]);
                acc[j4 * 4 + 3] = fmaf(xv.w, wv, acc[j4 * 4 + 3]);
            }
        }
    }

    size_t ob = (size_t)(b * 128 + oc) * 4096 + n0 + nh * 32;
#pragma unroll
    for (int j4 = 0; j4 < 8; ++j4) {
        float4 xr = *(const float4*)&x[ob + j4 * 4];
        float4 ov;
        ov.x = acc[j4 * 4 + 0] + xr.x;
        ov.y = acc[j4 * 4 + 1] + xr.y;
        ov.z = acc[j4 * 4 + 2] + xr.z;
        ov.w = acc[j4 * 4 + 3] + xr.w;
        *(float4*)&out[ob + j4 * 4] = ov;
    }
}

// ---------------- launch ----------------
extern "C" void kernel_launch(void* const* d_in, const int* in_sizes, int n_in,
                              void* d_out, int out_size, void* d_ws, size_t ws_size,
                              hipStream_t stream)
{
    const float* x     = (const float*)d_in[0];
    const float* gn_w  = (const float*)d_in[1];
    const float* gn_b  = (const float*)d_in[2];
    const float* qkv_w = (const float*)d_in[3];
    const float* qkv_b = (const float*)d_in[4];
    const float* out_w = (const float*)d_in[5];
    const float* out_b = (const float*)d_in[6];
    float* out = (float*)d_out;

    char* ws = (char*)d_ws;
    float* mean  = (float*)ws;                       // 128 f32
    float* rstd  = (float*)(ws + 512);               // 128 f32
    u16*   Q     = (u16*)(ws + 4096);                // (4,4096,128) bf16 = 4 MB
    u16*   K     = (u16*)(ws + 4198400);             // (4,4096,128) bf16 = 4 MB
    u16*   V     = (u16*)(ws + 8392704);             // (4,128,4096) bf16 = 4 MB
    float* Opart = (float*)(ws + 12587008);          // (2,4,4096,128) f32 = 16 MB
    float* mlb   = (float*)(ws + 29364224);          // (2,16384,2) f32 = 256 KB

    k_stats<<<128, 256, 0, stream>>>(x, mean, rstd);
    k_qkv<<<256, 384, 0, stream>>>(x, gn_w, gn_b, qkv_w, qkv_b, mean, rstd, Q, K, V);
    k_attn<<<512, 256, 0, stream>>>(Q, K, V, Opart, mlb);
    k_proj<<<256, 256, 0, stream>>>(Opart, mlb, x, out_w, out_b, out);
}

// Round 2
// 214.111 us; speedup vs baseline: 3.9069x; 3.9069x over previous
//
#include <hip/hip_runtime.h>

typedef unsigned short u16;
typedef __attribute__((ext_vector_type(8))) short bf16x8;   // 8 bf16 in 4 VGPRs
typedef __attribute__((ext_vector_type(4))) float f32x4;

__device__ __forceinline__ u16 f2bf(float f) {
    union { float f; unsigned u; } v; v.f = f;
    unsigned r = v.u + 0x7fffu + ((v.u >> 16) & 1u);   // RNE
    return (u16)(r >> 16);
}

// ---------------- Kernel 1: GroupNorm stats ----------------
// 128 blocks = (b,g); each group is 4 channels * 4096 spatial = 16384 contiguous floats.
__global__ __launch_bounds__(256)
void k_stats(const float* __restrict__ x, float* __restrict__ mean, float* __restrict__ rstd)
{
    int bg = blockIdx.x, t = threadIdx.x;
    const float4* xp = (const float4*)(x + (size_t)bg * 16384);
    float s1 = 0.f, s2 = 0.f;
#pragma unroll
    for (int i = 0; i < 16; ++i) {
        float4 v = xp[i * 256 + t];
        s1 += v.x + v.y + v.z + v.w;
        s2 += v.x * v.x + v.y * v.y + v.z * v.z + v.w * v.w;
    }
#pragma unroll
    for (int off = 32; off >= 1; off >>= 1) {
        s1 += __shfl_xor(s1, off);
        s2 += __shfl_xor(s2, off);
    }
    __shared__ float a1[4], a2[4];
    if ((t & 63) == 0) { a1[t >> 6] = s1; a2[t >> 6] = s2; }
    __syncthreads();
    if (t == 0) {
        float t1 = a1[0] + a1[1] + a1[2] + a1[3];
        float t2 = a2[0] + a2[1] + a2[2] + a2[3];
        float mu = t1 * (1.f / 16384.f);
        float var = t2 * (1.f / 16384.f) - mu * mu;
        mean[bg] = mu;
        rstd[bg] = rsqrtf(var + 1e-5f);
    }
}

// ---------------- Kernel 2: normalize + QKV pointwise GEMM ----------------
// grid 256 = (b, ntile of 64); 384 threads, thread t owns output channel o=t.
// Writes: Q,K as (b,n,c) bf16 (rows contiguous in c), V as (b,c,n) bf16 (transposed).
// NOTE: ALL acc[] indices must be compile-time constants (rule #20) — a partial
// unroll here previously spilled acc[64] to scratch (VGPR=48, 2.1 GB scratch
// writes, 710 us). Store loops are fully unrolled.
__global__ __launch_bounds__(384)
void k_qkv(const float* __restrict__ x, const float* __restrict__ gn_w, const float* __restrict__ gn_b,
           const float* __restrict__ qkv_w, const float* __restrict__ qkv_b,
           const float* __restrict__ mean, const float* __restrict__ rstd,
           u16* __restrict__ Qo, u16* __restrict__ Ko, u16* __restrict__ Vo)
{
    __shared__ float xn[128][64];   // 32 KB, [channel][n-local]
    int t = threadIdx.x;
    int b = blockIdx.x >> 6;
    int n0 = (blockIdx.x & 63) << 6;

    for (int e = t; e < 8192; e += 384) {
        int c = e >> 6, nn = e & 63;
        int bg = (b << 5) + (c >> 2);
        float sc = rstd[bg] * gn_w[c];
        float sh = gn_b[c] - mean[bg] * sc;
        xn[c][nn] = x[(size_t)(b * 128 + c) * 4096 + n0 + nn] * sc + sh;
    }
    __syncthreads();

    int o = t;                       // 0..383 output channel
    float acc[64];
    float bias = qkv_b[o];
#pragma unroll
    for (int j = 0; j < 64; ++j) acc[j] = bias;

    const float4* wrow = (const float4*)(qkv_w + (size_t)o * 128);
    for (int c4 = 0; c4 < 32; ++c4) {
        float4 w4 = wrow[c4];
#pragma unroll
        for (int i = 0; i < 4; ++i) {
            int c = c4 * 4 + i;
            float wv = (i == 0) ? w4.x : (i == 1) ? w4.y : (i == 2) ? w4.z : w4.w;
#pragma unroll
            for (int j4 = 0; j4 < 16; ++j4) {
                float4 xv = *(const float4*)&xn[c][j4 * 4];
                acc[j4 * 4 + 0] = fmaf(xv.x, wv, acc[j4 * 4 + 0]);
                acc[j4 * 4 + 1] = fmaf(xv.y, wv, acc[j4 * 4 + 1]);
                acc[j4 * 4 + 2] = fmaf(xv.z, wv, acc[j4 * 4 + 2]);
                acc[j4 * 4 + 3] = fmaf(xv.w, wv, acc[j4 * 4 + 3]);
            }
        }
    }

    if (o < 128) {                                   // Q -> (b,n,c)
        size_t base = (size_t)(b * 4096 + n0) * 128 + o;
#pragma unroll
        for (int nn = 0; nn < 64; ++nn) Qo[base + (size_t)nn * 128] = f2bf(acc[nn]);
    } else if (o < 256) {                            // K -> (b,n,c)
        size_t base = (size_t)(b * 4096 + n0) * 128 + (o - 128);
#pragma unroll
        for (int nn = 0; nn < 64; ++nn) Ko[base + (size_t)nn * 128] = f2bf(acc[nn]);
    } else {                                         // V -> (b,c,n), vectorized 8x bf16
        size_t base = (size_t)(b * 128 + (o - 256)) * 4096 + n0;
#pragma unroll
        for (int g = 0; g < 8; ++g) {
            uint4 pk;
            pk.x = ((unsigned)f2bf(acc[g * 8 + 1]) << 16) | f2bf(acc[g * 8 + 0]);
            pk.y = ((unsigned)f2bf(acc[g * 8 + 3]) << 16) | f2bf(acc[g * 8 + 2]);
            pk.z = ((unsigned)f2bf(acc[g * 8 + 5]) << 16) | f2bf(acc[g * 8 + 4]);
            pk.w = ((unsigned)f2bf(acc[g * 8 + 7]) << 16) | f2bf(acc[g * 8 + 6]);
            *(uint4*)&Vo[base + g * 8] = pk;
        }
    }
}

// ---------------- Kernel 3: flash attention (KV-split = 2) ----------------
// grid 512: blk = b*128 + qt*2 + half. 4 waves; wave w owns q rows q0+w*16..+15.
// mfma_f32_16x16x32_bf16: A lane: row=l&15, k=(l>>4)*8+j ; D lane: col=l&15, row=(l>>4)*4+r.
__global__ __launch_bounds__(256)
void k_attn(const u16* __restrict__ Qg, const u16* __restrict__ Kg, const u16* __restrict__ Vg,
            float* __restrict__ Opart, float* __restrict__ ml)
{
    __shared__ __align__(16) u16 Kl[64][136];    // padded: row stride 272B
    __shared__ __align__(16) u16 Vl[128][72];    // [c][kv-local], stride 144B
    __shared__ __align__(16) u16 Pl[4][16][72];  // per-wave P tile

    const int t = threadIdx.x;
    const int blk = blockIdx.x;
    const int half = blk & 1;
    const int qt = (blk >> 1) & 63;
    const int b = blk >> 7;
    const int w = t >> 6;
    const int lane = t & 63;
    const int l15 = lane & 15;
    const int l4 = lane >> 4;
    const int q0 = qt << 6;

    bf16x8 qf[4];
    {
        const u16* qb = Qg + (size_t)(b * 4096 + q0 + w * 16 + l15) * 128 + l4 * 8;
#pragma unroll
        for (int kc = 0; kc < 4; ++kc) qf[kc] = *(const bf16x8*)(qb + kc * 32);
    }
    f32x4 oac[8];
#pragma unroll
    for (int cf = 0; cf < 8; ++cf) oac[cf] = (f32x4){0.f, 0.f, 0.f, 0.f};
    float m[4], ls[4];
#pragma unroll
    for (int r = 0; r < 4; ++r) { m[r] = -__builtin_inff(); ls[r] = 0.f; }

    const int kvbeg = half << 11;
    const float scale = 0.08838834764831845f;   // 128^-0.5

    for (int kv0 = kvbeg; kv0 < kvbeg + 2048; kv0 += 64) {
        // stage K (64x128) and V^T (128x64) into LDS
#pragma unroll
        for (int i = 0; i < 4; ++i) {
            int e = i * 256 + t;
            int kr = e >> 4, kch = e & 15;
            *(uint4*)&Kl[kr][kch * 8] =
                *(const uint4*)(Kg + (size_t)(b * 4096 + kv0 + kr) * 128 + kch * 8);
            int vr = e >> 3, vch = e & 7;
            *(uint4*)&Vl[vr][vch * 8] =
                *(const uint4*)(Vg + (size_t)(b * 128 + vr) * 4096 + kv0 + vch * 8);
        }
        __syncthreads();

        // S = Q K^T * scale   (4 m-subtiles of 16)
        f32x4 st[4];
#pragma unroll
        for (int mt = 0; mt < 4; ++mt) {
            f32x4 s = (f32x4){0.f, 0.f, 0.f, 0.f};
#pragma unroll
            for (int kc = 0; kc < 4; ++kc) {
                bf16x8 kf = *(const bf16x8*)&Kl[mt * 16 + l15][kc * 32 + l4 * 8];
                s = __builtin_amdgcn_mfma_f32_16x16x32_bf16(qf[kc], kf, s, 0, 0, 0);
            }
#pragma unroll
            for (int r = 0; r < 4; ++r) st[mt][r] = s[r] * scale;
        }

        // online softmax: row groups are the 16 lanes sharing l>>4
        float rmax[4], rsum[4], fr[4];
#pragma unroll
        for (int r = 0; r < 4; ++r) {
            float v = fmaxf(fmaxf(st[0][r], st[1][r]), fmaxf(st[2][r], st[3][r]));
            v = fmaxf(v, __shfl_xor(v, 1));
            v = fmaxf(v, __shfl_xor(v, 2));
            v = fmaxf(v, __shfl_xor(v, 4));
            v = fmaxf(v, __shfl_xor(v, 8));
            rmax[r] = v;
        }
#pragma unroll
        for (int r = 0; r < 4; ++r) {
            float nm = fmaxf(m[r], rmax[r]);
            fr[r] = __expf(m[r] - nm);
            m[r] = nm;
            rsum[r] = 0.f;
        }
#pragma unroll
        for (int mt = 0; mt < 4; ++mt)
#pragma unroll
            for (int r = 0; r < 4; ++r) {
                float p = __expf(st[mt][r] - m[r]);
                st[mt][r] = p;
                rsum[r] += p;
            }
#pragma unroll
        for (int r = 0; r < 4; ++r) {
            float v = rsum[r];
            v += __shfl_xor(v, 1);
            v += __shfl_xor(v, 2);
            v += __shfl_xor(v, 4);
            v += __shfl_xor(v, 8);
            ls[r] = ls[r] * fr[r] + v;
        }
#pragma unroll
        for (int cf = 0; cf < 8; ++cf)
#pragma unroll
            for (int r = 0; r < 4; ++r) oac[cf][r] *= fr[r];

        // P (D-layout) -> LDS -> A-layout for PV
#pragma unroll
        for (int mt = 0; mt < 4; ++mt)
#pragma unroll
            for (int r = 0; r < 4; ++r)
                Pl[w][l4 * 4 + r][mt * 16 + l15] = f2bf(st[mt][r]);
        asm volatile("s_waitcnt lgkmcnt(0)" ::: "memory");
        __builtin_amdgcn_sched_barrier(0);

#pragma unroll
        for (int kc2 = 0; kc2 < 2; ++kc2) {
            bf16x8 pf = *(const bf16x8*)&Pl[w][l15][kc2 * 32 + l4 * 8];
#pragma unroll
            for (int cf = 0; cf < 8; ++cf) {
                bf16x8 vf = *(const bf16x8*)&Vl[cf * 16 + l15][kc2 * 32 + l4 * 8];
                oac[cf] = __builtin_amdgcn_mfma_f32_16x16x32_bf16(pf, vf, oac[cf], 0, 0, 0);
            }
        }
        __syncthreads();
    }

    // write unnormalized partials + (m, l)
    {
        size_t rb = ((size_t)half * 4 + b) * 4096 + q0 + w * 16 + l4 * 4;
#pragma unroll
        for (int cf = 0; cf < 8; ++cf)
#pragma unroll
            for (int r = 0; r < 4; ++r)
                Opart[(rb + r) * 128 + cf * 16 + l15] = oac[cf][r];
        if (l15 == 0) {
            size_t mb = (size_t)half * 16384 + b * 4096 + q0 + w * 16 + l4 * 4;
#pragma unroll
            for (int r = 0; r < 4; ++r) {
                ml[(mb + r) * 2 + 0] = m[r];
                ml[(mb + r) * 2 + 1] = ls[r];
            }
        }
    }
}

// ---------------- Kernel 4: merge halves + out-proj + bias + residual ----------------
// grid 256 = (b, ntile 64); 256 threads; thread owns oc=t&127, n-half nh=t>>7.
__global__ __launch_bounds__(256)
void k_proj(const float* __restrict__ Opart, const float* __restrict__ ml,
            const float* __restrict__ x, const float* __restrict__ out_w,
            const float* __restrict__ out_b, float* __restrict__ out)
{
    __shared__ float Ol[128][64];   // [c][n-local] merged attention output
    int t = threadIdx.x;
    int b = blockIdx.x >> 6;
    int n0 = (blockIdx.x & 63) << 6;

    for (int e = t; e < 2048; e += 256) {
        int nn = e >> 5, c4 = e & 31;
        size_t rg = (size_t)b * 4096 + n0 + nn;
        float m1 = ml[rg * 2], l1 = ml[rg * 2 + 1];
        float m2 = ml[(rg + 16384) * 2], l2 = ml[(rg + 16384) * 2 + 1];
        float mm = fmaxf(m1, m2);
        float e1 = __expf(m1 - mm), e2 = __expf(m2 - mm);
        float inv = 1.f / (l1 * e1 + l2 * e2);
        float4 o1 = *(const float4*)&Opart[rg * 128 + c4 * 4];
        float4 o2 = *(const float4*)&Opart[(rg + 16384) * 128 + c4 * 4];
        Ol[c4 * 4 + 0][nn] = (o1.x * e1 + o2.x * e2) * inv;
        Ol[c4 * 4 + 1][nn] = (o1.y * e1 + o2.y * e2) * inv;
        Ol[c4 * 4 + 2][nn] = (o1.z * e1 + o2.z * e2) * inv;
        Ol[c4 * 4 + 3][nn] = (o1.w * e1 + o2.w * e2) * inv;
    }
    __syncthreads();

    int oc = t & 127, nh = t >> 7;
    float acc[32];
    float bias = out_b[oc];
#pragma unroll
    for (int j = 0; j < 32; ++j) acc[j] = bias;

    const float4* wrow = (const float4*)(out_w + (size_t)oc * 128);
    for (int c4 = 0; c4 < 32; ++c4) {
        float4 w4 = wrow[c4];
#pragma unroll
        for (int i = 0; i < 4; ++i) {
            int c = c4 * 4 + i;
            float wv = (i == 0) ? w4.x : (i == 1) ? w4.y : (i == 2) ? w4.z : w4.w;
#pragma unroll
            for (int j4 = 0; j4 < 8; ++j4) {
                float4 xv = *(const float4*)&Ol[c][nh * 32 + j4 * 4];
                acc[j4 * 4 + 0] = fmaf(xv.x, wv, acc[j4 * 4 + 0]);
                acc[j4 * 4 + 1] = fmaf(xv.y, wv, acc[j4 * 4 + 1]);
                acc[j4 * 4 + 2] = fmaf(xv.z, wv, acc[j4 * 4 + 2]);
                acc[j4 * 4 + 3] = fmaf(xv.w, wv, acc[j4 * 4 + 3]);
            }
        }
    }

    size_t ob = (size_t)(b * 128 + oc) * 4096 + n0 + nh * 32;
#pragma unroll
    for (int j4 = 0; j4 < 8; ++j4) {
        float4 xr = *(const float4*)&x[ob + j4 * 4];
        float4 ov;
        ov.x = acc[j4 * 4 + 0] + xr.x;
        ov.y = acc[j4 * 4 + 1] + xr.y;
        ov.z = acc[j4 * 4 + 2] + xr.z;
        ov.w = acc[j4 * 4 + 3] + xr.w;
        *(float4*)&out[ob + j4 * 4] = ov;
    }
}

// ---------------- launch ----------------
extern "C" void kernel_launch(void* const* d_in, const int* in_sizes, int n_in,
                              void* d_out, int out_size, void* d_ws, size_t ws_size,
                              hipStream_t stream)
{
    const float* x     = (const float*)d_in[0];
    const float* gn_w  = (const float*)d_in[1];
    const float* gn_b  = (const float*)d_in[2];
    const float* qkv_w = (const float*)d_in[3];
    const float* qkv_b = (const float*)d_in[4];
    const float* out_w = (const float*)d_in[5];
    const float* out_b = (const float*)d_in[6];
    float* out = (float*)d_out;

    char* ws = (char*)d_ws;
    float* mean  = (float*)ws;                       // 128 f32
    float* rstd  = (float*)(ws + 512);               // 128 f32
    u16*   Q     = (u16*)(ws + 4096);                // (4,4096,128) bf16 = 4 MB
    u16*   K     = (u16*)(ws + 4198400);             // (4,4096,128) bf16 = 4 MB
    u16*   V     = (u16*)(ws + 8392704);             // (4,128,4096) bf16 = 4 MB
    float* Opart = (float*)(ws + 12587008);          // (2,4,4096,128) f32 = 16 MB
    float* mlb   = (float*)(ws + 29364224);          // (2,16384,2) f32 = 256 KB

    k_stats<<<128, 256, 0, stream>>>(x, mean, rstd);
    k_qkv<<<256, 384, 0, stream>>>(x, gn_w, gn_b, qkv_w, qkv_b, mean, rstd, Q, K, V);
    k_attn<<<512, 256, 0, stream>>>(Q, K, V, Opart, mlb);
    k_proj<<<256, 256, 0, stream>>>(Opart, mlb, x, out_w, out_b, out);
}